// Round 1
// baseline (1047.063 us; speedup 1.0000x reference)
//
#include <hip/hip_runtime.h>
#include <hip/hip_bf16.h>

typedef __attribute__((ext_vector_type(8))) short bf16x8;
typedef __attribute__((ext_vector_type(4))) float f32x4;

#define DEVI static __device__ __forceinline__

constexpr int DM  = 1024;   // d_model
constexpr int NH  = 16;     // heads
constexpr int DKH = 64;     // head dim
constexpr int FFD = 4096;
constexpr int BB  = 8;      // batch
constexpr int SEQ = 1024;
constexpr int TT  = BB * SEQ;  // 8192 tokens

DEVI float bf2f(unsigned short u) {
    union { unsigned u32; float f; } v; v.u32 = ((unsigned)u) << 16; return v.f;
}
DEVI unsigned short f2bf(float f) {
    union { float f; unsigned u; } v; v.f = f;
    unsigned x = v.u;
    return (unsigned short)((x + 0x7fffu + ((x >> 16) & 1u)) >> 16); // RNE
}

// ---------------------------------------------------------------- convert
__global__ __launch_bounds__(256) void k_cvt(const float* __restrict__ src,
                                             unsigned short* __restrict__ dst, int n) {
    int i = (blockIdx.x * 256 + threadIdx.x) * 4;
    if (i >= n) return;
    float4 v = *reinterpret_cast<const float4*>(src + i);
    ushort4 o;
    o.x = f2bf(v.x); o.y = f2bf(v.y); o.z = f2bf(v.z); o.w = f2bf(v.w);
    *reinterpret_cast<ushort4*>(dst + i) = o;
}

// ---------------------------------------------------------------- GEMM
// C[M,N] = act(A[M,K] @ W[N,K]^T + bias)   A,W,C bf16 (ushort bits), bias f32
// 128x128 tile, BK=32, 256 threads (4 waves, 2x2), each wave 64x64 via 4x4 MFMA tiles.
template <int ACT>
__global__ __launch_bounds__(256)
void k_gemm(const unsigned short* __restrict__ A,
            const unsigned short* __restrict__ W,
            const float* __restrict__ bias,
            unsigned short* __restrict__ C,
            int M, int N, int K) {
    constexpr int BK = 32, LDA = 40; // +8 pad: 80B row stride -> 2-way (free) on b128 reads
    __shared__ __align__(16) unsigned short As[128 * LDA];
    __shared__ __align__(16) unsigned short Bs[128 * LDA];
    const int tid  = threadIdx.x;
    const int lane = tid & 63, wave = tid >> 6;
    const int wm = wave & 1, wn = wave >> 1;
    const int l15 = lane & 15, quad = lane >> 4;
    const int m0 = blockIdx.y * 128;
    const int n0 = blockIdx.x * 128;

    f32x4 acc[4][4];
#pragma unroll
    for (int i = 0; i < 4; i++)
#pragma unroll
        for (int j = 0; j < 4; j++) acc[i][j] = (f32x4){0.f, 0.f, 0.f, 0.f};

    const int r0 = tid >> 2;          // 0..63
    const int c0 = (tid & 3) * 8;     // 0,8,16,24

    for (int kb = 0; kb < K; kb += BK) {
        __syncthreads();
        {
            uint4 a0 = *(const uint4*)(A + (size_t)(m0 + r0) * K + kb + c0);
            uint4 a1 = *(const uint4*)(A + (size_t)(m0 + 64 + r0) * K + kb + c0);
            uint4 b0 = *(const uint4*)(W + (size_t)(n0 + r0) * K + kb + c0);
            uint4 b1 = *(const uint4*)(W + (size_t)(n0 + 64 + r0) * K + kb + c0);
            *(uint4*)(As + r0 * LDA + c0) = a0;
            *(uint4*)(As + (64 + r0) * LDA + c0) = a1;
            *(uint4*)(Bs + r0 * LDA + c0) = b0;
            *(uint4*)(Bs + (64 + r0) * LDA + c0) = b1;
        }
        __syncthreads();
        bf16x8 af[4], bfv[4];
#pragma unroll
        for (int mt = 0; mt < 4; mt++)
            af[mt] = *(const bf16x8*)(As + (wm * 64 + mt * 16 + l15) * LDA + quad * 8);
#pragma unroll
        for (int nt = 0; nt < 4; nt++)
            bfv[nt] = *(const bf16x8*)(Bs + (wn * 64 + nt * 16 + l15) * LDA + quad * 8);
#pragma unroll
        for (int mt = 0; mt < 4; mt++)
#pragma unroll
            for (int nt = 0; nt < 4; nt++)
                acc[mt][nt] = __builtin_amdgcn_mfma_f32_16x16x32_bf16(af[mt], bfv[nt], acc[mt][nt], 0, 0, 0);
    }

#pragma unroll
    for (int mt = 0; mt < 4; mt++)
#pragma unroll
        for (int nt = 0; nt < 4; nt++) {
            const int col = n0 + wn * 64 + nt * 16 + l15;
            const float bv = bias[col];
#pragma unroll
            for (int r = 0; r < 4; r++) {
                const int row = m0 + wm * 64 + mt * 16 + quad * 4 + r;
                float v = acc[mt][nt][r] + bv;
                if (ACT == 1) v = v > 0.f ? v : 0.f;
                C[(size_t)row * N + col] = f2bf(v);
            }
        }
}

// ---------------------------------------------------------------- flash attention
// Q,K,V: bf16 [T, 1024] (token-major, head strided by 64). O: bf16 [T,1024].
// grid (SEQ/64, B*NH), 256 thr. Wave w owns 16 Q rows. KT=32 keys/iter.
__global__ __launch_bounds__(256)
void k_attn(const unsigned short* __restrict__ Q,
            const unsigned short* __restrict__ K,
            const unsigned short* __restrict__ V,
            unsigned short* __restrict__ O) {
    constexpr int KT = 32, LDK = 72, LDV = 40, LDP = 40;
    __shared__ __align__(16) unsigned short Ks[KT * LDK];   // [key][d]
    __shared__ __align__(16) unsigned short Vs[DKH * LDV];  // [d][key]  (transposed)
    __shared__ __align__(16) unsigned short Ps[4][16 * LDP];
    const int tid  = threadIdx.x;
    const int lane = tid & 63, wave = tid >> 6;
    const int l15 = lane & 15, quad = lane >> 4;
    const int bh = blockIdx.y;
    const int b = bh >> 4, h = bh & 15;
    const int q0 = blockIdx.x * 64 + wave * 16;      // within-batch row
    const size_t tbase = (size_t)b * SEQ * DM;       // element base of batch

    bf16x8 aq[2];
    {
        const size_t qoff = tbase + (size_t)(q0 + l15) * DM + h * DKH + quad * 8;
        aq[0] = *(const bf16x8*)(Q + qoff);
        aq[1] = *(const bf16x8*)(Q + qoff + 32);
    }
    f32x4 o_[4];
#pragma unroll
    for (int i = 0; i < 4; i++) o_[i] = (f32x4){0.f, 0.f, 0.f, 0.f};
    float m_[4], l_[4];
#pragma unroll
    for (int r = 0; r < 4; r++) { m_[r] = -1e30f; l_[r] = 0.f; }

    const int sr = tid >> 3;         // 0..31 key row
    const int sc = (tid & 7) * 8;    // 0..56 d chunk

    for (int kt = 0; kt < SEQ; kt += KT) {
        __syncthreads();
        {
            const size_t koff = tbase + (size_t)(kt + sr) * DM + h * DKH + sc;
            uint4 kv = *(const uint4*)(K + koff);
            *(uint4*)(Ks + sr * LDK + sc) = kv;
            uint4 vv = *(const uint4*)(V + koff);
            const unsigned short* vsp = (const unsigned short*)&vv;
#pragma unroll
            for (int j = 0; j < 8; j++) Vs[(sc + j) * LDV + sr] = vsp[j];
        }
        __syncthreads();

        f32x4 s[2];
#pragma unroll
        for (int ct = 0; ct < 2; ct++) {
            bf16x8 bk0 = *(const bf16x8*)(Ks + (ct * 16 + l15) * LDK + quad * 8);
            bf16x8 bk1 = *(const bf16x8*)(Ks + (ct * 16 + l15) * LDK + 32 + quad * 8);
            f32x4 t = (f32x4){0.f, 0.f, 0.f, 0.f};
            t = __builtin_amdgcn_mfma_f32_16x16x32_bf16(aq[0], bk0, t, 0, 0, 0);
            t = __builtin_amdgcn_mfma_f32_16x16x32_bf16(aq[1], bk1, t, 0, 0, 0);
            s[ct] = t * 0.125f;  // 1/sqrt(64)
        }

        float p[2][4];
#pragma unroll
        for (int r = 0; r < 4; r++) {
            float mx = fmaxf(s[0][r], s[1][r]);
#pragma unroll
            for (int off = 8; off; off >>= 1) mx = fmaxf(mx, __shfl_xor(mx, off));
            const float mnew  = fmaxf(m_[r], mx);
            const float alpha = __expf(m_[r] - mnew);
            const float p0 = __expf(s[0][r] - mnew);
            const float p1 = __expf(s[1][r] - mnew);
            float rs = p0 + p1;
#pragma unroll
            for (int off = 8; off; off >>= 1) rs += __shfl_xor(rs, off);
            l_[r] = l_[r] * alpha + rs;
            m_[r] = mnew;
            p[0][r] = p0; p[1][r] = p1;
#pragma unroll
            for (int nt = 0; nt < 4; nt++) o_[nt][r] *= alpha;
        }

        // P: C-layout -> A-layout via per-wave LDS slab
#pragma unroll
        for (int ct = 0; ct < 2; ct++)
#pragma unroll
            for (int r = 0; r < 4; r++)
                Ps[wave][(quad * 4 + r) * LDP + ct * 16 + l15] = f2bf(p[ct][r]);
        __asm__ volatile("s_waitcnt lgkmcnt(0)" ::: "memory");
        bf16x8 pa = *(const bf16x8*)(Ps[wave] + l15 * LDP + quad * 8);
#pragma unroll
        for (int nt = 0; nt < 4; nt++) {
            bf16x8 bv = *(const bf16x8*)(Vs + (nt * 16 + l15) * LDV + quad * 8);
            o_[nt] = __builtin_amdgcn_mfma_f32_16x16x32_bf16(pa, bv, o_[nt], 0, 0, 0);
        }
    }

#pragma unroll
    for (int nt = 0; nt < 4; nt++)
#pragma unroll
        for (int r = 0; r < 4; r++) {
            const size_t row = (size_t)b * SEQ + q0 + quad * 4 + r;
            const float v = o_[nt][r] / l_[r];
            O[row * DM + h * DKH + nt * 16 + l15] = f2bf(v);
        }
}

// ---------------------------------------------------------------- fused add + LayerNorm
// y = LN(xa + xb) * g + be ; inputs bf16, outputs bf16 (Y) and/or f32 (Yf)
__global__ __launch_bounds__(256)
void k_add_ln(const unsigned short* __restrict__ Xa,
              const unsigned short* __restrict__ Xb,
              const float* __restrict__ g, const float* __restrict__ be,
              unsigned short* __restrict__ Y, float* __restrict__ Yf) {
    const int row = blockIdx.x;
    const int base = threadIdx.x * 4;
    const size_t off = (size_t)row * DM + base;
    ushort4 xa = *(const ushort4*)(Xa + off);
    ushort4 xb = *(const ushort4*)(Xb + off);
    float v[4];
    v[0] = bf2f(xa.x) + bf2f(xb.x);
    v[1] = bf2f(xa.y) + bf2f(xb.y);
    v[2] = bf2f(xa.z) + bf2f(xb.z);
    v[3] = bf2f(xa.w) + bf2f(xb.w);
    float s1 = v[0] + v[1] + v[2] + v[3];
    float s2 = v[0]*v[0] + v[1]*v[1] + v[2]*v[2] + v[3]*v[3];
#pragma unroll
    for (int o = 32; o; o >>= 1) { s1 += __shfl_xor(s1, o); s2 += __shfl_xor(s2, o); }
    __shared__ float rs1[4], rs2[4];
    if ((threadIdx.x & 63) == 0) { rs1[threadIdx.x >> 6] = s1; rs2[threadIdx.x >> 6] = s2; }
    __syncthreads();
    s1 = rs1[0] + rs1[1] + rs1[2] + rs1[3];
    s2 = rs2[0] + rs2[1] + rs2[2] + rs2[3];
    const float mu = s1 * (1.f / DM);
    const float var = s2 * (1.f / DM) - mu * mu;
    const float rstd = rsqrtf(var + 1e-5f);
    float y[4];
#pragma unroll
    for (int j = 0; j < 4; j++) y[j] = (v[j] - mu) * rstd * g[base + j] + be[base + j];
    if (Y) {
        ushort4 o;
        o.x = f2bf(y[0]); o.y = f2bf(y[1]); o.z = f2bf(y[2]); o.w = f2bf(y[3]);
        *(ushort4*)(Y + off) = o;
    }
    if (Yf) *(float4*)(Yf + off) = (float4){y[0], y[1], y[2], y[3]};
}

// ---------------------------------------------------------------- launch
extern "C" void kernel_launch(void* const* d_in, const int* in_sizes, int n_in,
                              void* d_out, int out_size, void* d_ws, size_t ws_size,
                              hipStream_t stream) {
    const float* x    = (const float*)d_in[0];
    const float* mem  = (const float*)d_in[1];
    const float* Wq1  = (const float*)d_in[2];  const float* bq1 = (const float*)d_in[3];
    const float* Wk1  = (const float*)d_in[4];  const float* bk1 = (const float*)d_in[5];
    const float* Wv1  = (const float*)d_in[6];  const float* bv1 = (const float*)d_in[7];
    const float* Wq2  = (const float*)d_in[8];  const float* bq2 = (const float*)d_in[9];
    const float* Wk2  = (const float*)d_in[10]; const float* bk2 = (const float*)d_in[11];
    const float* Wv2  = (const float*)d_in[12]; const float* bv2 = (const float*)d_in[13];
    const float* W1   = (const float*)d_in[14]; const float* b1  = (const float*)d_in[15];
    const float* W2   = (const float*)d_in[16]; const float* b2  = (const float*)d_in[17];
    const float* g1   = (const float*)d_in[18]; const float* be1 = (const float*)d_in[19];
    const float* g2   = (const float*)d_in[20]; const float* be2 = (const float*)d_in[21];
    const float* g3   = (const float*)d_in[22]; const float* be3 = (const float*)d_in[23];
    float* out = (float*)d_out;

    const size_t MiB = 1u << 20;
    char* w = (char*)d_ws;
    unsigned short* Wq1b = (unsigned short*)(w + 0 * MiB);
    unsigned short* Wk1b = (unsigned short*)(w + 2 * MiB);
    unsigned short* Wv1b = (unsigned short*)(w + 4 * MiB);
    unsigned short* Wq2b = (unsigned short*)(w + 6 * MiB);
    unsigned short* Wk2b = (unsigned short*)(w + 8 * MiB);
    unsigned short* Wv2b = (unsigned short*)(w + 10 * MiB);
    unsigned short* W1b  = (unsigned short*)(w + 12 * MiB);  // 8 MiB
    unsigned short* W2b  = (unsigned short*)(w + 20 * MiB);  // 8 MiB
    unsigned short* xb   = (unsigned short*)(w + 28 * MiB);  // 16 MiB
    unsigned short* mb   = (unsigned short*)(w + 44 * MiB);
    unsigned short* Qb   = (unsigned short*)(w + 60 * MiB);
    unsigned short* Kb   = (unsigned short*)(w + 76 * MiB);
    unsigned short* Vb   = (unsigned short*)(w + 92 * MiB);
    unsigned short* Ab   = (unsigned short*)(w + 108 * MiB);
    unsigned short* x1b  = (unsigned short*)(w + 124 * MiB);
    unsigned short* x2b  = (unsigned short*)(w + 140 * MiB);
    unsigned short* h1b  = (unsigned short*)(w + 60 * MiB);   // 64 MiB, overlays Q/K/V/A (dead)
    unsigned short* h2b  = (unsigned short*)(w + 124 * MiB);  // overlays x1 (dead)

    const dim3 blk(256);
    // converts
    k_cvt<<<TT * DM / 1024, blk, 0, stream>>>(x,   xb,   TT * DM);
    k_cvt<<<TT * DM / 1024, blk, 0, stream>>>(mem, mb,   TT * DM);
    k_cvt<<<DM * DM / 1024, blk, 0, stream>>>(Wq1, Wq1b, DM * DM);
    k_cvt<<<DM * DM / 1024, blk, 0, stream>>>(Wk1, Wk1b, DM * DM);
    k_cvt<<<DM * DM / 1024, blk, 0, stream>>>(Wv1, Wv1b, DM * DM);
    k_cvt<<<DM * DM / 1024, blk, 0, stream>>>(Wq2, Wq2b, DM * DM);
    k_cvt<<<DM * DM / 1024, blk, 0, stream>>>(Wk2, Wk2b, DM * DM);
    k_cvt<<<DM * DM / 1024, blk, 0, stream>>>(Wv2, Wv2b, DM * DM);
    k_cvt<<<FFD * DM / 1024, blk, 0, stream>>>(W1, W1b, FFD * DM);
    k_cvt<<<FFD * DM / 1024, blk, 0, stream>>>(W2, W2b, FFD * DM);

    const dim3 gD(DM / 128, TT / 128);   // N=1024
    const dim3 gF(FFD / 128, TT / 128);  // N=4096
    const dim3 gA(SEQ / 64, BB * NH);

    // self-attention
    k_gemm<0><<<gD, blk, 0, stream>>>(xb, Wq1b, bq1, Qb, TT, DM, DM);
    k_gemm<0><<<gD, blk, 0, stream>>>(xb, Wk1b, bk1, Kb, TT, DM, DM);
    k_gemm<0><<<gD, blk, 0, stream>>>(xb, Wv1b, bv1, Vb, TT, DM, DM);
    k_attn<<<gA, blk, 0, stream>>>(Qb, Kb, Vb, Ab);
    k_add_ln<<<TT, blk, 0, stream>>>(xb, Ab, g1, be1, x1b, nullptr);
    // cross-attention
    k_gemm<0><<<gD, blk, 0, stream>>>(x1b, Wq2b, bq2, Qb, TT, DM, DM);
    k_gemm<0><<<gD, blk, 0, stream>>>(mb,  Wk2b, bk2, Kb, TT, DM, DM);
    k_gemm<0><<<gD, blk, 0, stream>>>(mb,  Wv2b, bv2, Vb, TT, DM, DM);
    k_attn<<<gA, blk, 0, stream>>>(Qb, Kb, Vb, Ab);
    k_add_ln<<<TT, blk, 0, stream>>>(x1b, Ab, g2, be2, x2b, nullptr);
    // FFN
    k_gemm<1><<<gF, blk, 0, stream>>>(x2b, W1b, b1, h1b, TT, FFD, DM);
    k_gemm<0><<<gD, blk, 0, stream>>>(h1b, W2b, b2, h2b, TT, DM, FFD);
    k_add_ln<<<TT, blk, 0, stream>>>(x2b, h2b, g3, be3, nullptr, out);
}

// Round 2
// 776.214 us; speedup vs baseline: 1.3489x; 1.3489x over previous
//
#include <hip/hip_runtime.h>
#include <hip/hip_bf16.h>

typedef __attribute__((ext_vector_type(8))) short bf16x8;
typedef __attribute__((ext_vector_type(4))) float f32x4;

#define DEVI static __device__ __forceinline__

constexpr int DM  = 1024;   // d_model
constexpr int NH  = 16;     // heads
constexpr int FFD = 4096;
constexpr int BB  = 8;      // batch
constexpr int SEQ = 1024;
constexpr int TT  = BB * SEQ;  // 8192 tokens

DEVI float bf2f(unsigned short u) {
    union { unsigned u32; float f; } v; v.u32 = ((unsigned)u) << 16; return v.f;
}
DEVI unsigned short f2bf(float f) {
    union { float f; unsigned u; } v; v.f = f;
    unsigned x = v.u;
    return (unsigned short)((x + 0x7fffu + ((x >> 16) & 1u)) >> 16); // RNE
}

// async 16B global->LDS. lds base must be wave-uniform; HW writes lane i at
// base + i*16 (m104/m108). Global addr is per-lane.
DEVI void async_ld16(void* lds, const void* g) {
    __builtin_amdgcn_global_load_lds(
        (const __attribute__((address_space(1))) unsigned int*)g,
        (__attribute__((address_space(3))) unsigned int*)lds, 16, 0, 0);
}

// ---------------------------------------------------------------- convert
__global__ __launch_bounds__(256) void k_cvt(const float* __restrict__ src,
                                             unsigned short* __restrict__ dst, int n) {
    int i = (blockIdx.x * 256 + threadIdx.x) * 4;
    if (i >= n) return;
    float4 v = *reinterpret_cast<const float4*>(src + i);
    ushort4 o;
    o.x = f2bf(v.x); o.y = f2bf(v.y); o.z = f2bf(v.z); o.w = f2bf(v.w);
    *reinterpret_cast<ushort4*>(dst + i) = o;
}

// ---------------------------------------------------------------- GEMM (m97 pattern)
// C[M,N] = act(A[M,K] @ W[N,K]^T + bias). 128x128 tile, BK=32,
// global_load_lds width-16 staging into unpadded [128][32] LDS (64B rows: free).
template <int ACT, int BIAS_ROW>
__global__ __launch_bounds__(256)
void k_gemm(const unsigned short* __restrict__ A,
            const unsigned short* __restrict__ W,
            const float* __restrict__ bias,
            unsigned short* __restrict__ C,
            int M, int N, int K) {
    __shared__ __align__(16) unsigned short As[128 * 32];
    __shared__ __align__(16) unsigned short Bs[128 * 32];
    const int tid  = threadIdx.x;
    const int lane = tid & 63, wave = tid >> 6;
    const int wm = wave & 1, wn = wave >> 1;
    const int l15 = lane & 15, quad = lane >> 4;
    const int m0 = blockIdx.y * 128;
    const int n0 = blockIdx.x * 128;

    f32x4 acc[4][4];
#pragma unroll
    for (int i = 0; i < 4; i++)
#pragma unroll
        for (int j = 0; j < 4; j++) acc[i][j] = (f32x4){0.f, 0.f, 0.f, 0.f};

    // staging: wave w covers rows [w*32, w*32+32) of both tiles, 2 segs of 16 rows.
    const int srow = lane >> 2;          // 0..15
    const int scol = (lane & 3) * 8;     // 0,8,16,24
    const unsigned short* Ag = A + (size_t)(m0 + wave * 32 + srow) * K + scol;
    const unsigned short* Wg = W + (size_t)(n0 + wave * 32 + srow) * K + scol;
    unsigned short* Al0 = As + (wave * 32) * 32;
    unsigned short* Al1 = As + (wave * 32 + 16) * 32;
    unsigned short* Bl0 = Bs + (wave * 32) * 32;
    unsigned short* Bl1 = Bs + (wave * 32 + 16) * 32;

    for (int kb = 0; kb < K; kb += 32) {
        __syncthreads();
        async_ld16(Al0, Ag + kb);
        async_ld16(Al1, Ag + (size_t)16 * K + kb);
        async_ld16(Bl0, Wg + kb);
        async_ld16(Bl1, Wg + (size_t)16 * K + kb);
        __syncthreads();
        bf16x8 af[4], bfv[4];
#pragma unroll
        for (int mt = 0; mt < 4; mt++)
            af[mt] = *(const bf16x8*)(As + (wm * 64 + mt * 16 + l15) * 32 + quad * 8);
#pragma unroll
        for (int nt = 0; nt < 4; nt++)
            bfv[nt] = *(const bf16x8*)(Bs + (wn * 64 + nt * 16 + l15) * 32 + quad * 8);
#pragma unroll
        for (int mt = 0; mt < 4; mt++)
#pragma unroll
            for (int nt = 0; nt < 4; nt++)
                acc[mt][nt] = __builtin_amdgcn_mfma_f32_16x16x32_bf16(af[mt], bfv[nt], acc[mt][nt], 0, 0, 0);
    }

#pragma unroll
    for (int mt = 0; mt < 4; mt++)
#pragma unroll
        for (int nt = 0; nt < 4; nt++) {
            const int col = n0 + wn * 64 + nt * 16 + l15;
            float bcol = BIAS_ROW ? 0.f : bias[col];
#pragma unroll
            for (int r = 0; r < 4; r++) {
                const int row = m0 + wm * 64 + mt * 16 + quad * 4 + r;
                float v = acc[mt][nt][r] + (BIAS_ROW ? bias[row] : bcol);
                if (ACT == 1) v = v > 0.f ? v : 0.f;
                C[(size_t)row * N + col] = f2bf(v);
            }
        }
}

// ---------------------------------------------------------------- flash attention (S^T orientation)
// Q,K: bf16 [T,1024] token-major. Vt: bf16 [1024,T] (d-major, from transposed GEMM).
// O: bf16 [T,1024]. grid (SEQ/128, B*NH), 256 thr. Wave owns 32 q rows; KT=64.
// S^T = mfma(K-rows, Q-rows): D[m=key][n=q] -> softmax stats are per-lane scalars,
// P exits in C-layout [key][q] -> packed ushort4 writes into Ps[q][key],
// O^T = mfma(Vt-rows, P-frag). K/Vt staged async with chunk^=(row&7) swizzle.
__global__ __launch_bounds__(256)
void k_attn(const unsigned short* __restrict__ Q,
            const unsigned short* __restrict__ K,
            const unsigned short* __restrict__ Vt,
            unsigned short* __restrict__ O) {
    constexpr int LDP = 72;
    __shared__ __align__(16) unsigned short Ks[64 * 64];  // [key][d]   swizzled chunks
    __shared__ __align__(16) unsigned short Vs[64 * 64];  // [d][key]   swizzled chunks
    __shared__ __align__(16) unsigned short Ps[4][32 * LDP];  // per wave: [q][key]
    const int tid  = threadIdx.x;
    const int lane = tid & 63, wave = tid >> 6;
    const int l15 = lane & 15, quad = lane >> 4;
    const int bh = blockIdx.y;
    const int b = bh >> 4, h = bh & 15;
    const int q0 = blockIdx.x * 128 + wave * 32;

    // Q frags: Y[n=q][k=d]
    bf16x8 aq[2][2];
#pragma unroll
    for (int ntQ = 0; ntQ < 2; ntQ++)
#pragma unroll
        for (int kc = 0; kc < 2; kc++)
            aq[ntQ][kc] = *(const bf16x8*)(Q + (size_t)(b * SEQ + q0 + ntQ * 16 + l15) * DM
                                             + h * 64 + kc * 32 + quad * 8);

    f32x4 o_[4][2];
#pragma unroll
    for (int i = 0; i < 4; i++)
#pragma unroll
        for (int j = 0; j < 2; j++) o_[i][j] = (f32x4){0.f, 0.f, 0.f, 0.f};
    float m_[2] = {-1e30f, -1e30f}, l_[2] = {0.f, 0.f};

    // staging lanes: 8 rows x 8 chunks per 1024B segment; swizzle on global side
    const int srow  = lane >> 3;                 // 0..7
    const int ctrue = (lane & 7) ^ srow;         // global 16B chunk within row
    const int seg0 = wave, seg1 = wave + 4;      // 8 segs per tile over 4 waves
    const unsigned short* Kg = K  + (size_t)(b * SEQ) * DM + h * 64 + ctrue * 8;
    const unsigned short* Vg = Vt + (size_t)(h * 64) * TT + b * SEQ + ctrue * 8;

    for (int kt = 0; kt < SEQ; kt += 64) {
        __syncthreads();
        async_ld16(Ks + seg0 * 512, Kg + (size_t)(kt + seg0 * 8 + srow) * DM);
        async_ld16(Ks + seg1 * 512, Kg + (size_t)(kt + seg1 * 8 + srow) * DM);
        async_ld16(Vs + seg0 * 512, Vg + (size_t)(seg0 * 8 + srow) * TT + kt);
        async_ld16(Vs + seg1 * 512, Vg + (size_t)(seg1 * 8 + srow) * TT + kt);
        __syncthreads();

        // S^T: D[m=key][n=q]
        f32x4 s[4][2];
#pragma unroll
        for (int i = 0; i < 4; i++)
#pragma unroll
            for (int j = 0; j < 2; j++) s[i][j] = (f32x4){0.f, 0.f, 0.f, 0.f};
#pragma unroll
        for (int kc = 0; kc < 2; kc++)
#pragma unroll
            for (int mtK = 0; mtK < 4; mtK++) {
                const int pos = (kc * 4 + quad) ^ (l15 & 7);
                bf16x8 kf = *(const bf16x8*)(Ks + (mtK * 16 + l15) * 64 + pos * 8);
#pragma unroll
                for (int ntQ = 0; ntQ < 2; ntQ++)
                    s[mtK][ntQ] = __builtin_amdgcn_mfma_f32_16x16x32_bf16(kf, aq[ntQ][kc], s[mtK][ntQ], 0, 0, 0);
            }

        // online softmax; q owned per-lane (col = l15), keys live in (quad, reg)
#pragma unroll
        for (int ntQ = 0; ntQ < 2; ntQ++) {
            float mx = -1e30f;
#pragma unroll
            for (int mtK = 0; mtK < 4; mtK++)
#pragma unroll
                for (int r = 0; r < 4; r++) mx = fmaxf(mx, s[mtK][ntQ][r]);
            mx = fmaxf(mx, __shfl_xor(mx, 16));
            mx = fmaxf(mx, __shfl_xor(mx, 32));
            const float mnew  = fmaxf(m_[ntQ], mx * 0.125f);
            const float alpha = __expf(m_[ntQ] - mnew);
            m_[ntQ] = mnew;
            float sum = 0.f;
#pragma unroll
            for (int mtK = 0; mtK < 4; mtK++) {
                float p0 = __expf(fmaf(s[mtK][ntQ][0], 0.125f, -mnew));
                float p1 = __expf(fmaf(s[mtK][ntQ][1], 0.125f, -mnew));
                float p2 = __expf(fmaf(s[mtK][ntQ][2], 0.125f, -mnew));
                float p3 = __expf(fmaf(s[mtK][ntQ][3], 0.125f, -mnew));
                sum += (p0 + p1) + (p2 + p3);
                ushort4 pk;
                pk.x = f2bf(p0); pk.y = f2bf(p1); pk.z = f2bf(p2); pk.w = f2bf(p3);
                *(ushort4*)(&Ps[wave][(ntQ * 16 + l15) * LDP + mtK * 16 + quad * 4]) = pk;
            }
            sum += __shfl_xor(sum, 16);
            sum += __shfl_xor(sum, 32);
            l_[ntQ] = l_[ntQ] * alpha + sum;
#pragma unroll
            for (int mtD = 0; mtD < 4; mtD++)
#pragma unroll
                for (int r = 0; r < 4; r++) o_[mtD][ntQ][r] *= alpha;
        }
        __asm__ volatile("s_waitcnt lgkmcnt(0)" ::: "memory");

        // O^T += mfma(Vt-frag, P-frag): D[m=d][n=q]
        bf16x8 pf[2][2];
#pragma unroll
        for (int ntQ = 0; ntQ < 2; ntQ++)
#pragma unroll
            for (int kc2 = 0; kc2 < 2; kc2++)
                pf[ntQ][kc2] = *(const bf16x8*)(&Ps[wave][(ntQ * 16 + l15) * LDP + kc2 * 32 + quad * 8]);
#pragma unroll
        for (int kc2 = 0; kc2 < 2; kc2++)
#pragma unroll
            for (int mtD = 0; mtD < 4; mtD++) {
                const int pos = (kc2 * 4 + quad) ^ (l15 & 7);
                bf16x8 vf = *(const bf16x8*)(Vs + (mtD * 16 + l15) * 64 + pos * 8);
#pragma unroll
                for (int ntQ = 0; ntQ < 2; ntQ++)
                    o_[mtD][ntQ] = __builtin_amdgcn_mfma_f32_16x16x32_bf16(vf, pf[ntQ][kc2], o_[mtD][ntQ], 0, 0, 0);
            }
    }

    // epilogue: O^T C-layout -> O[token][d], ushort4 over reg rows (4 consecutive d)
#pragma unroll
    for (int ntQ = 0; ntQ < 2; ntQ++) {
        const float rl = 1.f / l_[ntQ];
        const size_t tok = (size_t)b * SEQ + q0 + ntQ * 16 + l15;
#pragma unroll
        for (int mtD = 0; mtD < 4; mtD++) {
            ushort4 ov;
            ov.x = f2bf(o_[mtD][ntQ][0] * rl);
            ov.y = f2bf(o_[mtD][ntQ][1] * rl);
            ov.z = f2bf(o_[mtD][ntQ][2] * rl);
            ov.w = f2bf(o_[mtD][ntQ][3] * rl);
            *(ushort4*)(O + tok * DM + h * 64 + mtD * 16 + quad * 4) = ov;
        }
    }
}

// ---------------------------------------------------------------- fused add + LayerNorm
__global__ __launch_bounds__(256)
void k_add_ln(const unsigned short* __restrict__ Xa,
              const unsigned short* __restrict__ Xb,
              const float* __restrict__ g, const float* __restrict__ be,
              unsigned short* __restrict__ Y, float* __restrict__ Yf) {
    const int row = blockIdx.x;
    const int base = threadIdx.x * 4;
    const size_t off = (size_t)row * DM + base;
    ushort4 xa = *(const ushort4*)(Xa + off);
    ushort4 xb = *(const ushort4*)(Xb + off);
    float v[4];
    v[0] = bf2f(xa.x) + bf2f(xb.x);
    v[1] = bf2f(xa.y) + bf2f(xb.y);
    v[2] = bf2f(xa.z) + bf2f(xb.z);
    v[3] = bf2f(xa.w) + bf2f(xb.w);
    float s1 = v[0] + v[1] + v[2] + v[3];
    float s2 = v[0]*v[0] + v[1]*v[1] + v[2]*v[2] + v[3]*v[3];
#pragma unroll
    for (int o = 32; o; o >>= 1) { s1 += __shfl_xor(s1, o); s2 += __shfl_xor(s2, o); }
    __shared__ float rs1[4], rs2[4];
    if ((threadIdx.x & 63) == 0) { rs1[threadIdx.x >> 6] = s1; rs2[threadIdx.x >> 6] = s2; }
    __syncthreads();
    s1 = rs1[0] + rs1[1] + rs1[2] + rs1[3];
    s2 = rs2[0] + rs2[1] + rs2[2] + rs2[3];
    const float mu = s1 * (1.f / DM);
    const float var = s2 * (1.f / DM) - mu * mu;
    const float rstd = rsqrtf(var + 1e-5f);
    float y[4];
#pragma unroll
    for (int j = 0; j < 4; j++) y[j] = (v[j] - mu) * rstd * g[base + j] + be[base + j];
    if (Y) {
        ushort4 o;
        o.x = f2bf(y[0]); o.y = f2bf(y[1]); o.z = f2bf(y[2]); o.w = f2bf(y[3]);
        *(ushort4*)(Y + off) = o;
    }
    if (Yf) *(float4*)(Yf + off) = (float4){y[0], y[1], y[2], y[3]};
}

// ---------------------------------------------------------------- launch
extern "C" void kernel_launch(void* const* d_in, const int* in_sizes, int n_in,
                              void* d_out, int out_size, void* d_ws, size_t ws_size,
                              hipStream_t stream) {
    const float* x    = (const float*)d_in[0];
    const float* mem  = (const float*)d_in[1];
    const float* Wq1  = (const float*)d_in[2];  const float* bq1 = (const float*)d_in[3];
    const float* Wk1  = (const float*)d_in[4];  const float* bk1 = (const float*)d_in[5];
    const float* Wv1  = (const float*)d_in[6];  const float* bv1 = (const float*)d_in[7];
    const float* Wq2  = (const float*)d_in[8];  const float* bq2 = (const float*)d_in[9];
    const float* Wk2  = (const float*)d_in[10]; const float* bk2 = (const float*)d_in[11];
    const float* Wv2  = (const float*)d_in[12]; const float* bv2 = (const float*)d_in[13];
    const float* W1   = (const float*)d_in[14]; const float* b1  = (const float*)d_in[15];
    const float* W2   = (const float*)d_in[16]; const float* b2  = (const float*)d_in[17];
    const float* g1   = (const float*)d_in[18]; const float* be1 = (const float*)d_in[19];
    const float* g2   = (const float*)d_in[20]; const float* be2 = (const float*)d_in[21];
    const float* g3   = (const float*)d_in[22]; const float* be3 = (const float*)d_in[23];
    float* out = (float*)d_out;

    const size_t MiB = 1u << 20;
    char* w = (char*)d_ws;
    unsigned short* Wq1b = (unsigned short*)(w + 0 * MiB);
    unsigned short* Wk1b = (unsigned short*)(w + 2 * MiB);
    unsigned short* Wv1b = (unsigned short*)(w + 4 * MiB);
    unsigned short* Wq2b = (unsigned short*)(w + 6 * MiB);
    unsigned short* Wk2b = (unsigned short*)(w + 8 * MiB);
    unsigned short* Wv2b = (unsigned short*)(w + 10 * MiB);
    unsigned short* W1b  = (unsigned short*)(w + 12 * MiB);  // 8 MiB
    unsigned short* W2b  = (unsigned short*)(w + 20 * MiB);  // 8 MiB
    unsigned short* xb   = (unsigned short*)(w + 28 * MiB);  // 16 MiB
    unsigned short* mb   = (unsigned short*)(w + 44 * MiB);
    unsigned short* Qb   = (unsigned short*)(w + 60 * MiB);
    unsigned short* Kb   = (unsigned short*)(w + 76 * MiB);
    unsigned short* Vtb  = (unsigned short*)(w + 92 * MiB);  // [DM][TT] transposed
    unsigned short* Ab   = (unsigned short*)(w + 108 * MiB);
    unsigned short* x1b  = (unsigned short*)(w + 124 * MiB);
    unsigned short* x2b  = (unsigned short*)(w + 140 * MiB);
    unsigned short* h1b  = (unsigned short*)(w + 60 * MiB);   // 64 MiB, overlays Q/K/Vt/A (dead)
    unsigned short* h2b  = (unsigned short*)(w + 124 * MiB);  // overlays x1 (dead)

    const dim3 blk(256);
    k_cvt<<<TT * DM / 1024, blk, 0, stream>>>(x,   xb,   TT * DM);
    k_cvt<<<TT * DM / 1024, blk, 0, stream>>>(mem, mb,   TT * DM);
    k_cvt<<<DM * DM / 1024, blk, 0, stream>>>(Wq1, Wq1b, DM * DM);
    k_cvt<<<DM * DM / 1024, blk, 0, stream>>>(Wk1, Wk1b, DM * DM);
    k_cvt<<<DM * DM / 1024, blk, 0, stream>>>(Wv1, Wv1b, DM * DM);
    k_cvt<<<DM * DM / 1024, blk, 0, stream>>>(Wq2, Wq2b, DM * DM);
    k_cvt<<<DM * DM / 1024, blk, 0, stream>>>(Wk2, Wk2b, DM * DM);
    k_cvt<<<DM * DM / 1024, blk, 0, stream>>>(Wv2, Wv2b, DM * DM);
    k_cvt<<<FFD * DM / 1024, blk, 0, stream>>>(W1, W1b, FFD * DM);
    k_cvt<<<FFD * DM / 1024, blk, 0, stream>>>(W2, W2b, FFD * DM);

    const dim3 gD(DM / 128, TT / 128);    // C [TT, DM]
    const dim3 gVt(TT / 128, DM / 128);   // C [DM, TT] (transposed V)
    const dim3 gF(FFD / 128, TT / 128);
    const dim3 gA(SEQ / 128, BB * NH);

    // self-attention
    k_gemm<0,0><<<gD,  blk, 0, stream>>>(xb,   Wq1b, bq1, Qb,  TT, DM, DM);
    k_gemm<0,0><<<gD,  blk, 0, stream>>>(xb,   Wk1b, bk1, Kb,  TT, DM, DM);
    k_gemm<0,1><<<gVt, blk, 0, stream>>>(Wv1b, xb,   bv1, Vtb, DM, TT, DM);  // V^T
    k_attn<<<gA, blk, 0, stream>>>(Qb, Kb, Vtb, Ab);
    k_add_ln<<<TT, blk, 0, stream>>>(xb, Ab, g1, be1, x1b, nullptr);
    // cross-attention
    k_gemm<0,0><<<gD,  blk, 0, stream>>>(x1b,  Wq2b, bq2, Qb,  TT, DM, DM);
    k_gemm<0,0><<<gD,  blk, 0, stream>>>(mb,   Wk2b, bk2, Kb,  TT, DM, DM);
    k_gemm<0,1><<<gVt, blk, 0, stream>>>(Wv2b, mb,   bv2, Vtb, DM, TT, DM);  // V^T
    k_attn<<<gA, blk, 0, stream>>>(Qb, Kb, Vtb, Ab);
    k_add_ln<<<TT, blk, 0, stream>>>(x1b, Ab, g2, be2, x2b, nullptr);
    // FFN
    k_gemm<1,0><<<gF, blk, 0, stream>>>(x2b, W1b, b1, h1b, TT, FFD, DM);
    k_gemm<0,0><<<gD, blk, 0, stream>>>(h1b, W2b, b2, h2b, TT, DM, FFD);
    k_add_ln<<<TT, blk, 0, stream>>>(x2b, h2b, g3, be3, nullptr, out);
}

// Round 3
// 733.206 us; speedup vs baseline: 1.4281x; 1.0587x over previous
//
#include <hip/hip_runtime.h>
#include <hip/hip_bf16.h>

typedef __attribute__((ext_vector_type(8))) short bf16x8;
typedef __attribute__((ext_vector_type(4))) float f32x4;

#define DEVI static __device__ __forceinline__

constexpr int DM  = 1024;   // d_model
constexpr int NH  = 16;     // heads
constexpr int FFD = 4096;
constexpr int BB  = 8;      // batch
constexpr int SEQ = 1024;
constexpr int TT  = BB * SEQ;  // 8192 tokens

DEVI float bf2f(unsigned short u) {
    union { unsigned u32; float f; } v; v.u32 = ((unsigned)u) << 16; return v.f;
}
DEVI unsigned short f2bf(float f) {
    union { float f; unsigned u; } v; v.f = f;
    unsigned x = v.u;
    return (unsigned short)((x + 0x7fffu + ((x >> 16) & 1u)) >> 16); // RNE
}

DEVI void async_ld16(void* lds, const void* g) {
    __builtin_amdgcn_global_load_lds(
        (const __attribute__((address_space(1))) unsigned int*)g,
        (__attribute__((address_space(3))) unsigned int*)lds, 16, 0, 0);
}

// ---------------------------------------------------------------- mega convert
// one launch for all 10 fp32->bf16 conversions. Regions sized in 1024-elem blocks.
__global__ __launch_bounds__(256)
void k_cvt_all(const float* __restrict__ s0, unsigned short* __restrict__ d0,   // x    8M
               const float* __restrict__ s1, unsigned short* __restrict__ d1,   // mem  8M
               const float* __restrict__ s2, unsigned short* __restrict__ d2,   // Wq1  1M
               const float* __restrict__ s3, unsigned short* __restrict__ d3,   // Wk1
               const float* __restrict__ s4, unsigned short* __restrict__ d4,   // Wv1
               const float* __restrict__ s5, unsigned short* __restrict__ d5,   // Wq2
               const float* __restrict__ s6, unsigned short* __restrict__ d6,   // Wk2
               const float* __restrict__ s7, unsigned short* __restrict__ d7,   // Wv2
               const float* __restrict__ s8, unsigned short* __restrict__ d8,   // W1   4M
               const float* __restrict__ s9, unsigned short* __restrict__ d9) { // W2   4M
    int b = blockIdx.x;
    const float* s; unsigned short* d;
    if      (b < 8192)  { s = s0; d = d0; }
    else if (b < 16384) { s = s1; d = d1; b -= 8192; }
    else if (b < 17408) { s = s2; d = d2; b -= 16384; }
    else if (b < 18432) { s = s3; d = d3; b -= 17408; }
    else if (b < 19456) { s = s4; d = d4; b -= 18432; }
    else if (b < 20480) { s = s5; d = d5; b -= 19456; }
    else if (b < 21504) { s = s6; d = d6; b -= 20480; }
    else if (b < 22528) { s = s7; d = d7; b -= 21504; }
    else if (b < 26624) { s = s8; d = d8; b -= 22528; }
    else                { s = s9; d = d9; b -= 26624; }
    const int i = (b * 256 + threadIdx.x) * 4;
    float4 v = *reinterpret_cast<const float4*>(s + i);
    ushort4 o;
    o.x = f2bf(v.x); o.y = f2bf(v.y); o.z = f2bf(v.z); o.w = f2bf(v.w);
    *reinterpret_cast<ushort4*>(d + i) = o;
}

// ---------------------------------------------------------------- GEMM (m97 pattern + XCD swizzle)
// C[M,N] = act(A[M,K] @ W[N,K]^T + bias). 128x128 tile, BK=32, global_load_lds.
// SWZ=1: A-strips (rows) XCD-exclusive (use when A is the big operand; gridY%8==0).
// SWZ=2: W-strips (cols) XCD-exclusive (use when W is the big operand; gridX%8==0).
// bias: col<Nsplit ? bias1[col] : bias2[col-Nsplit]  (pass bias2=bias1,Nsplit=N if single)
template <int ACT, int BIAS_ROW, int SWZ>
__global__ __launch_bounds__(256)
void k_gemm(const unsigned short* __restrict__ A,
            const unsigned short* __restrict__ W,
            const float* __restrict__ bias1, const float* __restrict__ bias2,
            unsigned short* __restrict__ C,
            int M, int N, int K, int Nsplit) {
    __shared__ __align__(16) unsigned short As[128 * 32];
    __shared__ __align__(16) unsigned short Bs[128 * 32];
    const int tid  = threadIdx.x;
    const int lane = tid & 63, wave = tid >> 6;
    const int wm = wave & 1, wn = wave >> 1;
    const int l15 = lane & 15, quad = lane >> 4;

    int bx, by;
    if (SWZ == 1) {
        const int id = blockIdx.y * gridDim.x + blockIdx.x;
        const int xcd = id & 7, i2 = id >> 3;
        bx = i2 % gridDim.x;
        by = (i2 / gridDim.x) * 8 + xcd;
    } else if (SWZ == 2) {
        const int id = blockIdx.y * gridDim.x + blockIdx.x;
        const int xcd = id & 7, i2 = id >> 3;
        by = i2 % gridDim.y;
        bx = (i2 / gridDim.y) * 8 + xcd;
    } else { bx = blockIdx.x; by = blockIdx.y; }
    const int m0 = by * 128;
    const int n0 = bx * 128;

    f32x4 acc[4][4];
#pragma unroll
    for (int i = 0; i < 4; i++)
#pragma unroll
        for (int j = 0; j < 4; j++) acc[i][j] = (f32x4){0.f, 0.f, 0.f, 0.f};

    const int srow = lane >> 2;          // 0..15
    const int scol = (lane & 3) * 8;     // 0,8,16,24
    const unsigned short* Ag = A + (size_t)(m0 + wave * 32 + srow) * K + scol;
    const unsigned short* Wg = W + (size_t)(n0 + wave * 32 + srow) * K + scol;
    unsigned short* Al0 = As + (wave * 32) * 32;
    unsigned short* Al1 = As + (wave * 32 + 16) * 32;
    unsigned short* Bl0 = Bs + (wave * 32) * 32;
    unsigned short* Bl1 = Bs + (wave * 32 + 16) * 32;

    for (int kb = 0; kb < K; kb += 32) {
        __syncthreads();
        async_ld16(Al0, Ag + kb);
        async_ld16(Al1, Ag + (size_t)16 * K + kb);
        async_ld16(Bl0, Wg + kb);
        async_ld16(Bl1, Wg + (size_t)16 * K + kb);
        __syncthreads();
        bf16x8 af[4], bfv[4];
#pragma unroll
        for (int mt = 0; mt < 4; mt++)
            af[mt] = *(const bf16x8*)(As + (wm * 64 + mt * 16 + l15) * 32 + quad * 8);
#pragma unroll
        for (int nt = 0; nt < 4; nt++)
            bfv[nt] = *(const bf16x8*)(Bs + (wn * 64 + nt * 16 + l15) * 32 + quad * 8);
#pragma unroll
        for (int mt = 0; mt < 4; mt++)
#pragma unroll
            for (int nt = 0; nt < 4; nt++)
                acc[mt][nt] = __builtin_amdgcn_mfma_f32_16x16x32_bf16(af[mt], bfv[nt], acc[mt][nt], 0, 0, 0);
    }

#pragma unroll
    for (int mt = 0; mt < 4; mt++)
#pragma unroll
        for (int nt = 0; nt < 4; nt++) {
            const int col = n0 + wn * 64 + nt * 16 + l15;
            float bcol = 0.f;
            if (!BIAS_ROW) bcol = col < Nsplit ? bias1[col] : bias2[col - Nsplit];
#pragma unroll
            for (int r = 0; r < 4; r++) {
                const int row = m0 + wm * 64 + mt * 16 + quad * 4 + r;
                float v = acc[mt][nt][r] + (BIAS_ROW ? bias1[row] : bcol);
                if (ACT == 1) v = v > 0.f ? v : 0.f;
                C[(size_t)row * N + col] = f2bf(v);
            }
        }
}

// ---------------------------------------------------------------- flash attention (S^T orientation)
// Q [T, qld], K [T, kld] token-major; Vt [1024, T] d-major. O bf16 [T,1024].
__global__ __launch_bounds__(256)
void k_attn(const unsigned short* __restrict__ Q,
            const unsigned short* __restrict__ K,
            const unsigned short* __restrict__ Vt,
            unsigned short* __restrict__ O,
            int qld, int kld) {
    constexpr int LDP = 72;
    __shared__ __align__(16) unsigned short Ks[64 * 64];  // [key][d]   swizzled chunks
    __shared__ __align__(16) unsigned short Vs[64 * 64];  // [d][key]   swizzled chunks
    __shared__ __align__(16) unsigned short Ps[4][32 * LDP];  // per wave: [q][key]
    const int tid  = threadIdx.x;
    const int lane = tid & 63, wave = tid >> 6;
    const int l15 = lane & 15, quad = lane >> 4;
    const int bh = blockIdx.y;
    const int b = bh >> 4, h = bh & 15;
    const int q0 = blockIdx.x * 128 + wave * 32;

    bf16x8 aq[2][2];
#pragma unroll
    for (int ntQ = 0; ntQ < 2; ntQ++)
#pragma unroll
        for (int kc = 0; kc < 2; kc++)
            aq[ntQ][kc] = *(const bf16x8*)(Q + (size_t)(b * SEQ + q0 + ntQ * 16 + l15) * qld
                                             + h * 64 + kc * 32 + quad * 8);

    f32x4 o_[4][2];
#pragma unroll
    for (int i = 0; i < 4; i++)
#pragma unroll
        for (int j = 0; j < 2; j++) o_[i][j] = (f32x4){0.f, 0.f, 0.f, 0.f};
    float m_[2] = {-1e30f, -1e30f}, l_[2] = {0.f, 0.f};

    const int srow  = lane >> 3;                 // 0..7
    const int ctrue = (lane & 7) ^ srow;         // swizzled 16B chunk
    const int seg0 = wave, seg1 = wave + 4;
    const unsigned short* Kg = K  + (size_t)(b * SEQ) * kld + h * 64 + ctrue * 8;
    const unsigned short* Vg = Vt + (size_t)(h * 64) * TT + b * SEQ + ctrue * 8;

    for (int kt = 0; kt < SEQ; kt += 64) {
        __syncthreads();
        async_ld16(Ks + seg0 * 512, Kg + (size_t)(kt + seg0 * 8 + srow) * kld);
        async_ld16(Ks + seg1 * 512, Kg + (size_t)(kt + seg1 * 8 + srow) * kld);
        async_ld16(Vs + seg0 * 512, Vg + (size_t)(seg0 * 8 + srow) * TT + kt);
        async_ld16(Vs + seg1 * 512, Vg + (size_t)(seg1 * 8 + srow) * TT + kt);
        __syncthreads();

        f32x4 s[4][2];
#pragma unroll
        for (int i = 0; i < 4; i++)
#pragma unroll
            for (int j = 0; j < 2; j++) s[i][j] = (f32x4){0.f, 0.f, 0.f, 0.f};
#pragma unroll
        for (int kc = 0; kc < 2; kc++)
#pragma unroll
            for (int mtK = 0; mtK < 4; mtK++) {
                const int pos = (kc * 4 + quad) ^ (l15 & 7);
                bf16x8 kf = *(const bf16x8*)(Ks + (mtK * 16 + l15) * 64 + pos * 8);
#pragma unroll
                for (int ntQ = 0; ntQ < 2; ntQ++)
                    s[mtK][ntQ] = __builtin_amdgcn_mfma_f32_16x16x32_bf16(kf, aq[ntQ][kc], s[mtK][ntQ], 0, 0, 0);
            }

#pragma unroll
        for (int ntQ = 0; ntQ < 2; ntQ++) {
            float mx = -1e30f;
#pragma unroll
            for (int mtK = 0; mtK < 4; mtK++)
#pragma unroll
                for (int r = 0; r < 4; r++) mx = fmaxf(mx, s[mtK][ntQ][r]);
            mx = fmaxf(mx, __shfl_xor(mx, 16));
            mx = fmaxf(mx, __shfl_xor(mx, 32));
            const float mnew  = fmaxf(m_[ntQ], mx * 0.125f);
            const float alpha = __expf(m_[ntQ] - mnew);
            m_[ntQ] = mnew;
            float sum = 0.f;
#pragma unroll
            for (int mtK = 0; mtK < 4; mtK++) {
                float p0 = __expf(fmaf(s[mtK][ntQ][0], 0.125f, -mnew));
                float p1 = __expf(fmaf(s[mtK][ntQ][1], 0.125f, -mnew));
                float p2 = __expf(fmaf(s[mtK][ntQ][2], 0.125f, -mnew));
                float p3 = __expf(fmaf(s[mtK][ntQ][3], 0.125f, -mnew));
                sum += (p0 + p1) + (p2 + p3);
                ushort4 pk;
                pk.x = f2bf(p0); pk.y = f2bf(p1); pk.z = f2bf(p2); pk.w = f2bf(p3);
                *(ushort4*)(&Ps[wave][(ntQ * 16 + l15) * LDP + mtK * 16 + quad * 4]) = pk;
            }
            sum += __shfl_xor(sum, 16);
            sum += __shfl_xor(sum, 32);
            l_[ntQ] = l_[ntQ] * alpha + sum;
#pragma unroll
            for (int mtD = 0; mtD < 4; mtD++)
#pragma unroll
                for (int r = 0; r < 4; r++) o_[mtD][ntQ][r] *= alpha;
        }
        __asm__ volatile("s_waitcnt lgkmcnt(0)" ::: "memory");

        bf16x8 pf[2][2];
#pragma unroll
        for (int ntQ = 0; ntQ < 2; ntQ++)
#pragma unroll
            for (int kc2 = 0; kc2 < 2; kc2++)
                pf[ntQ][kc2] = *(const bf16x8*)(&Ps[wave][(ntQ * 16 + l15) * LDP + kc2 * 32 + quad * 8]);
#pragma unroll
        for (int kc2 = 0; kc2 < 2; kc2++)
#pragma unroll
            for (int mtD = 0; mtD < 4; mtD++) {
                const int pos = (kc2 * 4 + quad) ^ (l15 & 7);
                bf16x8 vf = *(const bf16x8*)(Vs + (mtD * 16 + l15) * 64 + pos * 8);
#pragma unroll
                for (int ntQ = 0; ntQ < 2; ntQ++)
                    o_[mtD][ntQ] = __builtin_amdgcn_mfma_f32_16x16x32_bf16(vf, pf[ntQ][kc2], o_[mtD][ntQ], 0, 0, 0);
            }
    }

#pragma unroll
    for (int ntQ = 0; ntQ < 2; ntQ++) {
        const float rl = 1.f / l_[ntQ];
        const size_t tok = (size_t)b * SEQ + q0 + ntQ * 16 + l15;
#pragma unroll
        for (int mtD = 0; mtD < 4; mtD++) {
            ushort4 ov;
            ov.x = f2bf(o_[mtD][ntQ][0] * rl);
            ov.y = f2bf(o_[mtD][ntQ][1] * rl);
            ov.z = f2bf(o_[mtD][ntQ][2] * rl);
            ov.w = f2bf(o_[mtD][ntQ][3] * rl);
            *(ushort4*)(O + tok * DM + h * 64 + mtD * 16 + quad * 4) = ov;
        }
    }
}

// ---------------------------------------------------------------- fused add + LayerNorm
__global__ __launch_bounds__(256)
void k_add_ln(const unsigned short* __restrict__ Xa,
              const unsigned short* __restrict__ Xb,
              const float* __restrict__ g, const float* __restrict__ be,
              unsigned short* __restrict__ Y, float* __restrict__ Yf) {
    const int row = blockIdx.x;
    const int base = threadIdx.x * 4;
    const size_t off = (size_t)row * DM + base;
    ushort4 xa = *(const ushort4*)(Xa + off);
    ushort4 xb = *(const ushort4*)(Xb + off);
    float v[4];
    v[0] = bf2f(xa.x) + bf2f(xb.x);
    v[1] = bf2f(xa.y) + bf2f(xb.y);
    v[2] = bf2f(xa.z) + bf2f(xb.z);
    v[3] = bf2f(xa.w) + bf2f(xb.w);
    float s1 = v[0] + v[1] + v[2] + v[3];
    float s2 = v[0]*v[0] + v[1]*v[1] + v[2]*v[2] + v[3]*v[3];
#pragma unroll
    for (int o = 32; o; o >>= 1) { s1 += __shfl_xor(s1, o); s2 += __shfl_xor(s2, o); }
    __shared__ float rs1[4], rs2[4];
    if ((threadIdx.x & 63) == 0) { rs1[threadIdx.x >> 6] = s1; rs2[threadIdx.x >> 6] = s2; }
    __syncthreads();
    s1 = rs1[0] + rs1[1] + rs1[2] + rs1[3];
    s2 = rs2[0] + rs2[1] + rs2[2] + rs2[3];
    const float mu = s1 * (1.f / DM);
    const float var = s2 * (1.f / DM) - mu * mu;
    const float rstd = rsqrtf(var + 1e-5f);
    float y[4];
#pragma unroll
    for (int j = 0; j < 4; j++) y[j] = (v[j] - mu) * rstd * g[base + j] + be[base + j];
    if (Y) {
        ushort4 o;
        o.x = f2bf(y[0]); o.y = f2bf(y[1]); o.z = f2bf(y[2]); o.w = f2bf(y[3]);
        *(ushort4*)(Y + off) = o;
    }
    if (Yf) *(float4*)(Yf + off) = (float4){y[0], y[1], y[2], y[3]};
}

// ---------------------------------------------------------------- launch
extern "C" void kernel_launch(void* const* d_in, const int* in_sizes, int n_in,
                              void* d_out, int out_size, void* d_ws, size_t ws_size,
                              hipStream_t stream) {
    const float* x    = (const float*)d_in[0];
    const float* mem  = (const float*)d_in[1];
    const float* Wq1  = (const float*)d_in[2];  const float* bq1 = (const float*)d_in[3];
    const float* Wk1  = (const float*)d_in[4];  const float* bk1 = (const float*)d_in[5];
    const float* Wv1  = (const float*)d_in[6];  const float* bv1 = (const float*)d_in[7];
    const float* Wq2  = (const float*)d_in[8];  const float* bq2 = (const float*)d_in[9];
    const float* Wk2  = (const float*)d_in[10]; const float* bk2 = (const float*)d_in[11];
    const float* Wv2  = (const float*)d_in[12]; const float* bv2 = (const float*)d_in[13];
    const float* W1   = (const float*)d_in[14]; const float* b1  = (const float*)d_in[15];
    const float* W2   = (const float*)d_in[16]; const float* b2  = (const float*)d_in[17];
    const float* g1   = (const float*)d_in[18]; const float* be1 = (const float*)d_in[19];
    const float* g2   = (const float*)d_in[20]; const float* be2 = (const float*)d_in[21];
    const float* g3   = (const float*)d_in[22]; const float* be3 = (const float*)d_in[23];
    float* out = (float*)d_out;

    const size_t MiB = 1u << 20;
    char* w = (char*)d_ws;
    unsigned short* Wq1b = (unsigned short*)(w + 0 * MiB);   // Wq1b/Wk1b adjacent => QK concat
    unsigned short* Wk1b = (unsigned short*)(w + 2 * MiB);
    unsigned short* Wv1b = (unsigned short*)(w + 4 * MiB);
    unsigned short* Wq2b = (unsigned short*)(w + 6 * MiB);
    unsigned short* Wk2b = (unsigned short*)(w + 8 * MiB);
    unsigned short* Wv2b = (unsigned short*)(w + 10 * MiB);
    unsigned short* W1b  = (unsigned short*)(w + 12 * MiB);
    unsigned short* W2b  = (unsigned short*)(w + 20 * MiB);
    unsigned short* xb   = (unsigned short*)(w + 28 * MiB);
    unsigned short* mb   = (unsigned short*)(w + 44 * MiB);
    unsigned short* QKb  = (unsigned short*)(w + 60 * MiB);  // self: [TT,2048] (32 MiB)
    unsigned short* Qb2  = (unsigned short*)(w + 60 * MiB);  // cross: [TT,1024]
    unsigned short* Kb2  = (unsigned short*)(w + 76 * MiB);  // cross: [TT,1024]
    unsigned short* Vtb  = (unsigned short*)(w + 92 * MiB);  // [DM][TT]
    unsigned short* Ab   = (unsigned short*)(w + 108 * MiB);
    unsigned short* x1b  = (unsigned short*)(w + 124 * MiB);
    unsigned short* x2b  = (unsigned short*)(w + 140 * MiB);
    unsigned short* h1b  = (unsigned short*)(w + 60 * MiB);   // 64 MiB, overlays QK/Vt/Ab (dead)
    unsigned short* h2b  = (unsigned short*)(w + 124 * MiB);  // overlays x1 (dead)

    const dim3 blk(256);
    k_cvt_all<<<30720, blk, 0, stream>>>(x, xb, mem, mb, Wq1, Wq1b, Wk1, Wk1b,
                                         Wv1, Wv1b, Wq2, Wq2b, Wk2, Wk2b,
                                         Wv2, Wv2b, W1, W1b, W2, W2b);

    const dim3 gD(DM / 128, TT / 128);     // N=1024
    const dim3 gQK(2048 / 128, TT / 128);  // N=2048 fused QK
    const dim3 gVt(TT / 128, DM / 128);    // C [DM, TT]
    const dim3 gF(FFD / 128, TT / 128);
    const dim3 gA(SEQ / 128, BB * NH);

    // self-attention
    k_gemm<0,0,1><<<gQK, blk, 0, stream>>>(xb,   Wq1b, bq1, bk1, QKb, TT, 2048, DM, 1024);
    k_gemm<0,1,2><<<gVt, blk, 0, stream>>>(Wv1b, xb,   bv1, bv1, Vtb, DM, TT, DM, TT);
    k_attn<<<gA, blk, 0, stream>>>(QKb, QKb + 1024, Vtb, Ab, 2048, 2048);
    k_add_ln<<<TT, blk, 0, stream>>>(xb, Ab, g1, be1, x1b, nullptr);
    // cross-attention
    k_gemm<0,0,1><<<gD,  blk, 0, stream>>>(x1b,  Wq2b, bq2, bq2, Qb2, TT, DM, DM, DM);
    k_gemm<0,0,1><<<gD,  blk, 0, stream>>>(mb,   Wk2b, bk2, bk2, Kb2, TT, DM, DM, DM);
    k_gemm<0,1,2><<<gVt, blk, 0, stream>>>(Wv2b, mb,   bv2, bv2, Vtb, DM, TT, DM, TT);
    k_attn<<<gA, blk, 0, stream>>>(Qb2, Kb2, Vtb, Ab, 1024, 1024);
    k_add_ln<<<TT, blk, 0, stream>>>(x1b, Ab, g2, be2, x2b, nullptr);
    // FFN
    k_gemm<1,0,0><<<gF, blk, 0, stream>>>(x2b, W1b, b1, b1, h1b, TT, FFD, DM, FFD);
    k_gemm<0,0,1><<<gD, blk, 0, stream>>>(h1b, W2b, b2, b2, h2b, TT, DM, FFD, DM);
    k_add_ln<<<TT, blk, 0, stream>>>(x2b, h2b, g3, be3, nullptr, out);
}